// Round 2
// baseline (430.944 us; speedup 1.0000x reference)
//
#include <hip/hip_runtime.h>

#define N_ 4
#define D_ 16
#define H_ 112
#define W_ 112
#define C_ 64

#define DO_ 2
#define HO_ 2
#define DT_ (D_ / DO_)                    // 8 d-tiles
#define HTILES (H_ / HO_)                 // 56 h-tiles
#define WAVES_PER_BLOCK 4
#define HGROUPS (HTILES / WAVES_PER_BLOCK) // 14
#define WSPLIT 4
#define WCHUNK (W_ / WSPLIT)              // 28

// Zero page: 64 floats in d_ws, read by all out-of-range halo streams.
__global__ void zero_page_kernel(float* zp) { zp[threadIdx.x] = 0.0f; }

// Register sliding-window depthwise 3D conv.
// lane = channel (C=64 == wave width) -> every global access is 256B coalesced.
// Each wave: fixed (n, d0..d0+1, h0..h0+1), slides over 28 w columns keeping a
// 3-column x 4x4 (d,h) input window in registers. Out-of-range (d,h) streams
// point at a zero page with step 0 (no per-iter mask multiplies).
__global__ __launch_bounds__(256)
void dwconv3d_kernel(const float* __restrict__ x,
                     const float* __restrict__ wgt,
                     float* __restrict__ out,
                     const float* __restrict__ zp) {
    int b = blockIdx.x;
    const int wh = b % WSPLIT;  b /= WSPLIT;
    const int hg = b % HGROUPS; b /= HGROUPS;
    const int dt = b % DT_;     b /= DT_;
    const int n  = b;

    const int lane = threadIdx.x & 63;
    const int wid  = threadIdx.x >> 6;
    const int c    = lane;

    const int d0 = dt * DO_;
    const int h0 = (hg * WAVES_PER_BLOCK + wid) * HO_;
    const int w0 = wh * WCHUNK;

    // per-lane weights wt[kd][kh][kw] (27 VGPRs), coalesced 256B loads
    float wt[3][3][3];
#pragma unroll
    for (int kd = 0; kd < 3; ++kd)
#pragma unroll
      for (int kh = 0; kh < 3; ++kh)
#pragma unroll
        for (int kw = 0; kw < 3; ++kw)
          wt[kd][kh][kw] = wgt[((kd * 3 + kh) * 3 + kw) * C_ + c];

    // 16 input streams: running pointer q (at column w0) + per-stream step
    // (C_ for valid streams, 0 for out-of-range -> stuck on zero page).
    const float* q[4][4];
    int step[4][4];
#pragma unroll
    for (int dr = 0; dr < 4; ++dr) {
      int d = d0 - 1 + dr;
#pragma unroll
      for (int hr = 0; hr < 4; ++hr) {
        int h = h0 - 1 + hr;
        bool valid = (d >= 0) && (d < D_) && (h >= 0) && (h < H_);
        if (valid) {
          q[dr][hr] = x + (size_t)((n * D_ + d) * H_ + h) * W_ * C_
                        + (size_t)w0 * C_ + c;
          step[dr][hr] = C_;
        } else {
          q[dr][hr] = zp + c;
          step[dr][hr] = 0;
        }
      }
    }

    // window: win[wslot][dr][hr], wslot 0/1/2 = cols w-1, w, w+1
    float win[3][4][4];

    if (w0 == 0) {          // wave-uniform
#pragma unroll
      for (int dr = 0; dr < 4; ++dr)
#pragma unroll
        for (int hr = 0; hr < 4; ++hr)
          win[0][dr][hr] = 0.0f;
    } else {
#pragma unroll
      for (int dr = 0; dr < 4; ++dr)
#pragma unroll
        for (int hr = 0; hr < 4; ++hr)
          win[0][dr][hr] = q[dr][hr][-step[dr][hr]];  // masked: zp -> 0
    }
#pragma unroll
    for (int dr = 0; dr < 4; ++dr)
#pragma unroll
      for (int hr = 0; hr < 4; ++hr) {
        win[1][dr][hr] = q[dr][hr][0];
        win[2][dr][hr] = q[dr][hr][step[dr][hr]];
        q[dr][hr] += 2 * step[dr][hr];   // now pointing at column w0+2
      }

    // output pointers (all 4 outputs always in-range)
    float* po[2][2];
#pragma unroll
    for (int od = 0; od < 2; ++od)
#pragma unroll
      for (int oh = 0; oh < 2; ++oh)
        po[od][oh] = out + ((size_t)((n * D_ + d0 + od) * H_ + (h0 + oh)) * W_ + w0) * C_ + c;

#pragma unroll 4
    for (int w = w0; w < w0 + WCHUNK; ++w) {
      float acc[2][2];
#pragma unroll
      for (int od = 0; od < 2; ++od)
#pragma unroll
        for (int oh = 0; oh < 2; ++oh) {
          float a = 0.0f;
#pragma unroll
          for (int kw = 0; kw < 3; ++kw)
#pragma unroll
            for (int kd = 0; kd < 3; ++kd)
#pragma unroll
              for (int kh = 0; kh < 3; ++kh)
                a += win[kw][od + kd][oh + kh] * wt[kd][kh][kw];
          acc[od][oh] = a;
        }
#pragma unroll
      for (int od = 0; od < 2; ++od)
#pragma unroll
        for (int oh = 0; oh < 2; ++oh) {
          *po[od][oh] = acc[od][oh];
          po[od][oh] += C_;
        }
      // rotate window (copies vanish under unroll)
#pragma unroll
      for (int dr = 0; dr < 4; ++dr)
#pragma unroll
        for (int hr = 0; hr < 4; ++hr) {
          win[0][dr][hr] = win[1][dr][hr];
          win[1][dr][hr] = win[2][dr][hr];
        }
      if (w + 2 < W_) {  // wave-uniform (only last chunk's tail hits else)
#pragma unroll
        for (int dr = 0; dr < 4; ++dr)
#pragma unroll
          for (int hr = 0; hr < 4; ++hr) {
            win[2][dr][hr] = q[dr][hr][0];
            q[dr][hr] += step[dr][hr];
          }
      } else {
#pragma unroll
        for (int dr = 0; dr < 4; ++dr)
#pragma unroll
          for (int hr = 0; hr < 4; ++hr)
            win[2][dr][hr] = 0.0f;
      }
    }
}

extern "C" void kernel_launch(void* const* d_in, const int* in_sizes, int n_in,
                              void* d_out, int out_size, void* d_ws, size_t ws_size,
                              hipStream_t stream) {
    const float* x   = (const float*)d_in[0];
    const float* wgt = (const float*)d_in[1];
    float* out = (float*)d_out;
    float* zp  = (float*)d_ws;   // 64 floats, zeroed below (ws is poisoned 0xAA)

    zero_page_kernel<<<1, 64, 0, stream>>>(zp);

    dim3 grid(N_ * DT_ * HGROUPS * WSPLIT);  // 4*8*14*4 = 1792 blocks
    dim3 block(256);
    dwconv3d_kernel<<<grid, block, 0, stream>>>(x, wgt, out, zp);
}